// Round 1
// baseline (1417.683 us; speedup 1.0000x reference)
//
#include <hip/hip_runtime.h>
#include <math.h>

// Problem constants (from setup_inputs): image_batch (32,1,512,512) f32, angles (8,) f32
#define N_IMG 32
#define N_ANG 8
#define H_ 512
#define W_ 512

// One thread handles 4 consecutive x pixels for one (k, y), looping over all 32
// batch images. Coordinates/weights are shared across n (they depend only on
// k,y,x) -> computed once, amortized 32x. Stores are float4-coalesced.
__global__ __launch_bounds__(256) void rotate_kernel(
    const float* __restrict__ img,     // [N_IMG][H][W]
    const float* __restrict__ angles,  // [N_ANG] degrees
    float* __restrict__ out)           // [N_IMG][N_ANG][H][W]
{
    const int k  = blockIdx.z;                               // angle index
    const int y  = blockIdx.y * blockDim.y + threadIdx.y;    // output row
    const int x4 = threadIdx.x * 4;                          // first of 4 output cols

    const float rad = angles[k] * 0.017453292519943295f;     // deg2rad, f32 like jnp
    float sa, ca;
    sincosf(rad, &sa, &ca);

    const float cx = (W_ - 1) * 0.5f;
    const float cy = (H_ - 1) * 0.5f;
    const float yr = (float)y - cy;

    int   o00[4], o01[4], o10[4], o11[4];
    float w00[4], w01[4], w10[4], w11[4];

#pragma unroll
    for (int j = 0; j < 4; ++j) {
        const float xr = (float)(x4 + j) - cx;
        const float sx = ca * xr - sa * yr + cx;
        const float sy = sa * xr + ca * yr + cy;
        const float x0f = floorf(sx);
        const float y0f = floorf(sy);
        const float wx = sx - x0f;
        const float wy = sy - y0f;
        const int x0 = (int)x0f;
        const int y0 = (int)y0f;
        const int x1 = x0 + 1;
        const int y1 = y0 + 1;
        // validity (zero-padding) folded into weights; clamped offsets for address
        const bool vx0 = ((unsigned)x0 < (unsigned)W_);
        const bool vx1 = ((unsigned)x1 < (unsigned)W_);
        const bool vy0 = ((unsigned)y0 < (unsigned)H_);
        const bool vy1 = ((unsigned)y1 < (unsigned)H_);
        const int x0c = min(max(x0, 0), W_ - 1);
        const int x1c = min(max(x1, 0), W_ - 1);
        const int y0c = min(max(y0, 0), H_ - 1);
        const int y1c = min(max(y1, 0), H_ - 1);
        o00[j] = y0c * W_ + x0c;
        o01[j] = y0c * W_ + x1c;
        o10[j] = y1c * W_ + x0c;
        o11[j] = y1c * W_ + x1c;
        const float omwx = 1.0f - wx;
        const float omwy = 1.0f - wy;
        w00[j] = omwy * omwx * (float)(vy0 && vx0);
        w01[j] = omwy * wx   * (float)(vy0 && vx1);
        w10[j] = wy   * omwx * (float)(vy1 && vx0);
        w11[j] = wy   * wx   * (float)(vy1 && vx1);
    }

#pragma unroll 4
    for (int n = 0; n < N_IMG; ++n) {
        const float* __restrict__ ib = img + (long)n * (H_ * W_);
        float r[4];
#pragma unroll
        for (int j = 0; j < 4; ++j) {
            r[j] = w00[j] * ib[o00[j]]
                 + w01[j] * ib[o01[j]]
                 + w10[j] * ib[o10[j]]
                 + w11[j] * ib[o11[j]];
        }
        float4* dst = (float4*)(out + (((long)(n * N_ANG + k)) * H_ + y) * W_ + x4);
        *dst = make_float4(r[0], r[1], r[2], r[3]);
    }
}

extern "C" void kernel_launch(void* const* d_in, const int* in_sizes, int n_in,
                              void* d_out, int out_size, void* d_ws, size_t ws_size,
                              hipStream_t stream) {
    const float* img    = (const float*)d_in[0];
    const float* angles = (const float*)d_in[1];
    float* out          = (float*)d_out;

    // block: 128 threads cover a full row (4 px each) x 2 rows = 256 threads
    dim3 block(128, 2, 1);
    dim3 grid(1, H_ / 2, N_ANG);   // 2048 blocks -> 8 blocks/CU, 32 waves/CU
    rotate_kernel<<<grid, block, 0, stream>>>(img, angles, out);
}

// Round 2
// 587.130 us; speedup vs baseline: 2.4146x; 2.4146x over previous
//
#include <hip/hip_runtime.h>
#include <math.h>

// Problem constants: image_batch (32,1,512,512) f32, angles (8,) f32
#define N_IMG 32
#define N_ANG 8
#define H_ 512
#define W_ 512

// Output tile per block: 64 (x) by 32 (y).
// Rotated source footprint of a 64x32 tile: <= ceil(sqrt(63^2+31^2)) + 4 = 75
// in each dimension -> stage in LDS [80 rows x pitch 81] = 25.9 KB.
#define TX 64
#define TY 32
#define LROWS 80
#define LPITCH 81   // odd pitch: good bank spread for gathers

__global__ __launch_bounds__(256) void rotate_tile_kernel(
    const float* __restrict__ img,     // [N_IMG][H][W]
    const float* __restrict__ angles,  // [N_ANG] degrees
    float* __restrict__ out)           // [N_IMG][N_ANG][H][W]
{
    __shared__ float tile[LROWS * LPITCH];

    const int k   = blockIdx.z;
    const int tx0 = blockIdx.x * TX;
    const int ty0 = blockIdx.y * TY;
    const int tid = threadIdx.x;       // 0..255
    const int lane = tid & 63;

    const float rad = angles[k] * 0.017453292519943295f;
    float sa, ca;
    sincosf(rad, &sa, &ca);
    const float cx = (W_ - 1) * 0.5f;
    const float cy = (H_ - 1) * 0.5f;

    // ---- source-footprint bbox for this tile (uniform across block) ----
    float minsx = 1e30f, maxsx = -1e30f, minsy = 1e30f, maxsy = -1e30f;
#pragma unroll
    for (int cyi = 0; cyi < 2; ++cyi) {
#pragma unroll
        for (int cxi = 0; cxi < 2; ++cxi) {
            const float xr = (float)(tx0 + cxi * (TX - 1)) - cx;
            const float yr = (float)(ty0 + cyi * (TY - 1)) - cy;
            const float sx = ca * xr - sa * yr + cx;
            const float sy = sa * xr + ca * yr + cy;
            minsx = fminf(minsx, sx); maxsx = fmaxf(maxsx, sx);
            minsy = fminf(minsy, sy); maxsy = fmaxf(maxsy, sy);
        }
    }
    int bx0 = (int)floorf(minsx) - 1;
    int bx1 = (int)floorf(maxsx) + 2;   // covers x1 = x0+1, + rounding margin
    int by0 = (int)floorf(minsy) - 1;
    int by1 = (int)floorf(maxsy) + 2;
    bx0 = min(max(bx0, 0), W_ - 1); bx1 = min(max(bx1, 0), W_ - 1);
    by0 = min(max(by0, 0), H_ - 1); by1 = min(max(by1, 0), H_ - 1);
    int bw = bx1 - bx0 + 1;
    int bh = by1 - by0 + 1;
    bw = min(bw, LPITCH);               // safety; never triggers (<=75)
    bh = min(bh, LROWS);

    // ---- per-thread sample coords/weights: depend only on (k,x,y),
    //      computed ONCE, reused for all 32 images ----
    // thread -> 2 passes of (row = tid>>4 + 16*p, cols = (tid&15)*4 .. +3)
    int   o00[2][4], o01[2][4], o10[2][4], o11[2][4];
    float w00[2][4], w01[2][4], w10[2][4], w11[2][4];
#pragma unroll
    for (int p = 0; p < 2; ++p) {
        const int yy = ty0 + (tid >> 4) + p * 16;
        const float yr = (float)yy - cy;
#pragma unroll
        for (int j = 0; j < 4; ++j) {
            const int xx = tx0 + (tid & 15) * 4 + j;
            const float xr = (float)xx - cx;
            const float sx = ca * xr - sa * yr + cx;
            const float sy = sa * xr + ca * yr + cy;
            const float x0f = floorf(sx), y0f = floorf(sy);
            const float wx = sx - x0f,   wy = sy - y0f;
            const int x0 = (int)x0f, y0 = (int)y0f;
            const int x1 = x0 + 1,   y1 = y0 + 1;
            const bool vx0 = ((unsigned)x0 < (unsigned)W_);
            const bool vx1 = ((unsigned)x1 < (unsigned)W_);
            const bool vy0 = ((unsigned)y0 < (unsigned)H_);
            const bool vy1 = ((unsigned)y1 < (unsigned)H_);
            // local (bbox) coords; clamped into bbox — weight is 0 when invalid
            const int lx0 = min(max(x0 - bx0, 0), bw - 1);
            const int lx1 = min(max(x1 - bx0, 0), bw - 1);
            const int ly0 = min(max(y0 - by0, 0), bh - 1);
            const int ly1 = min(max(y1 - by0, 0), bh - 1);
            o00[p][j] = ly0 * LPITCH + lx0;
            o01[p][j] = ly0 * LPITCH + lx1;
            o10[p][j] = ly1 * LPITCH + lx0;
            o11[p][j] = ly1 * LPITCH + lx1;
            const float omwx = 1.0f - wx, omwy = 1.0f - wy;
            w00[p][j] = omwy * omwx * (float)(vy0 && vx0);
            w01[p][j] = omwy * wx   * (float)(vy0 && vx1);
            w10[p][j] = wy   * omwx * (float)(vy1 && vx0);
            w11[p][j] = wy   * wx   * (float)(vy1 && vx1);
        }
    }

    // ---- per-image: stage bbox into LDS (coalesced rows), gather from LDS ----
    for (int n = 0; n < N_IMG; ++n) {
        const float* __restrict__ ib = img + (size_t)n * (H_ * W_);
        for (int ly = (tid >> 6); ly < bh; ly += 4) {
            const float* __restrict__ src = ib + (by0 + ly) * W_ + bx0;
            float* dstrow = tile + ly * LPITCH;
            for (int lx = lane; lx < bw; lx += 64)
                dstrow[lx] = src[lx];
        }
        __syncthreads();

        float* __restrict__ outn =
            out + ((size_t)(n * N_ANG + k) * H_ + ty0) * W_ + tx0;
#pragma unroll
        for (int p = 0; p < 2; ++p) {
            float v[4];
#pragma unroll
            for (int j = 0; j < 4; ++j) {
                v[j] = w00[p][j] * tile[o00[p][j]]
                     + w01[p][j] * tile[o01[p][j]]
                     + w10[p][j] * tile[o10[p][j]]
                     + w11[p][j] * tile[o11[p][j]];
            }
            const int row = (tid >> 4) + p * 16;
            float4* dst = (float4*)(outn + row * W_ + (tid & 15) * 4);
            *dst = make_float4(v[0], v[1], v[2], v[3]);
        }
        __syncthreads();   // protect LDS before next image's load
    }
}

extern "C" void kernel_launch(void* const* d_in, const int* in_sizes, int n_in,
                              void* d_out, int out_size, void* d_ws, size_t ws_size,
                              hipStream_t stream) {
    const float* img    = (const float*)d_in[0];
    const float* angles = (const float*)d_in[1];
    float* out          = (float*)d_out;

    dim3 block(256, 1, 1);
    dim3 grid(W_ / TX, H_ / TY, N_ANG);  // 8 x 16 x 8 = 1024 blocks
    rotate_tile_kernel<<<grid, block, 0, stream>>>(img, angles, out);
}

// Round 3
// 353.234 us; speedup vs baseline: 4.0134x; 1.6622x over previous
//
#include <hip/hip_runtime.h>
#include <math.h>
#include <stdint.h>

// image_batch (32,1,512,512) f32, angles (8,) f32 -> out (32,8,512,512) f32
#define N_IMG 32
#define N_ANG 8
#define H_ 512
#define W_ 512

// Output tile 64x32. Rotated source footprint <= ~71 px/axis; with floor/ceil
// margins (+3), 4-alignment (-3) and the 1-row/4-col derived-tap margin the
// staged bbox is <= 76 rows x <= 81 cols. LDS layout: pitch 84 words
// (bank stride 84%32=20 -> good spread), 25 chunks of 256 words = 6400 words
// = 25.6 KB -> 6 blocks/CU by LDS.
#define TX 64
#define TY 32
#define LP 84
#define NCHUNK 25
#define LWORDS (NCHUNK * 256)

__global__ __launch_bounds__(256, 5) void rotate_tile_kernel(
    const float* __restrict__ img,     // [N_IMG][H][W]
    const float* __restrict__ angles,  // [N_ANG] degrees
    float* __restrict__ out)           // [N_IMG][N_ANG][H][W]
{
    __shared__ float tile[LWORDS];

    const int bz   = blockIdx.z;
    const int k    = bz >> 1;                  // angle
    const int n0   = (bz & 1) * (N_IMG / 2);   // image half
    const int tx0  = blockIdx.x * TX;
    const int ty0  = blockIdx.y * TY;
    const int tid  = threadIdx.x;
    const int wid  = tid >> 6;
    const int lane = tid & 63;

    const float rad = angles[k] * 0.017453292519943295f;
    float sa, ca;
    sincosf(rad, &sa, &ca);
    const float cx = (W_ - 1) * 0.5f;
    const float cy = (H_ - 1) * 0.5f;

    // ---- source bbox (block-uniform) from the 4 tile corners ----
    float minsx = 1e30f, maxsx = -1e30f, minsy = 1e30f, maxsy = -1e30f;
#pragma unroll
    for (int cyi = 0; cyi < 2; ++cyi) {
#pragma unroll
        for (int cxi = 0; cxi < 2; ++cxi) {
            const float xr = (float)(tx0 + cxi * (TX - 1)) - cx;
            const float yr = (float)(ty0 + cyi * (TY - 1)) - cy;
            const float sx = ca * xr - sa * yr + cx;
            const float sy = sa * xr + ca * yr + cy;
            minsx = fminf(minsx, sx); maxsx = fmaxf(maxsx, sx);
            minsy = fminf(minsy, sy); maxsy = fmaxf(maxsy, sy);
        }
    }
    const int bx0 = min(max((int)floorf(minsx) - 1, 0), W_ - 1);
    const int by0 = min(max((int)floorf(minsy) - 1, 0), H_ - 1);
    // margined origins: one extra staged row and 4-col group at top/left so
    // taps x1=x0+1 / y1=y0+1 are always base+1 / base+LP (derived offsets
    // stay exact at the image boundary).
    const int bx0m = (bx0 & ~3) - 4;   // multiple of 4 (possibly negative)
    const int by0m = by0 - 1;

    // ---- per-lane staging source offsets: computed ONCE, reused 16 images.
    // Flat LDS word f -> (row,col) with pitch 84 (col stays mult-of-4, so a
    // lane's 16B never crosses an LDS row). Global side clamped in-bounds;
    // clamped (garbage) words are only ever gathered with weight 0.
    int goff[7];
    int nst = 0;
    for (int s = wid; s < NCHUNK; s += 4) {
        const int f   = s * 256 + lane * 4;
        const int row = f / LP;
        const int col = f - row * LP;
        const int grow = min(max(by0m + row, 0), H_ - 1);
        const int gcol = min(max(bx0m + col, 0), W_ - 4);
        goff[nst++] = grow * W_ + gcol;
    }

    // ---- lane -> output-pixel mapping, chosen per angle to spread LDS banks:
    // lanes along x when |cos|>=|sin| (near-horizontal source rows), along y
    // otherwise. Block-uniform -> no divergence.
    const bool modeA = fabsf(ca) >= fabsf(sa);
    const int pxg = modeA ? (tid & 15) : (tid >> 4);
    const int py0 = modeA ? (tid >> 4) : (tid & 15);
    const int px  = pxg * 4;

    // ---- per-pixel base LDS offset + 4 bilinear weights (image-independent)
    int   ob[2][4];
    float w00[2][4], w01[2][4], w10[2][4], w11[2][4];
#pragma unroll
    for (int p = 0; p < 2; ++p) {
        const int   yy = ty0 + py0 + p * 16;
        const float yr = (float)yy - cy;
#pragma unroll
        for (int j = 0; j < 4; ++j) {
            const int   xx = tx0 + px + j;
            const float xr = (float)xx - cx;
            const float sxs = ca * xr - sa * yr + cx;
            const float sys = sa * xr + ca * yr + cy;
            const float x0f = floorf(sxs), y0f = floorf(sys);
            const float wx = sxs - x0f, wy = sys - y0f;
            const int x0 = (int)x0f, y0 = (int)y0f;
            const bool vx0 = ((unsigned)x0       < (unsigned)W_);
            const bool vx1 = ((unsigned)(x0 + 1) < (unsigned)W_);
            const bool vy0 = ((unsigned)y0       < (unsigned)H_);
            const bool vy1 = ((unsigned)(y0 + 1) < (unsigned)H_);
            // valid taps are never clamped (margins guarantee range);
            // clamping only keeps weight-0 taps inside the LDS array.
            const int lx = min(max(x0 - bx0m, 0), 82);
            const int ly = min(max(y0 - by0m, 0), 74);
            ob[p][j] = ly * LP + lx;
            const float omwx = 1.0f - wx, omwy = 1.0f - wy;
            w00[p][j] = omwy * omwx * (float)(vy0 && vx0);
            w01[p][j] = omwy * wx   * (float)(vy0 && vx1);
            w10[p][j] = wy   * omwx * (float)(vy1 && vx0);
            w11[p][j] = wy   * wx   * (float)(vy1 && vx1);
        }
    }

    // ---- per-image: async-stage bbox into LDS, gather, store ----
    for (int n = n0; n < n0 + N_IMG / 2; ++n) {
        const float* __restrict__ ib = img + (size_t)n * (H_ * W_);
        for (int i = 0; i < nst; ++i) {
            __builtin_amdgcn_global_load_lds(
                (const __attribute__((address_space(1))) void*)(ib + goff[i]),
                (__attribute__((address_space(3))) void*)(&tile[(wid + i * 4) * 256]),
                16, 0, 0);
        }
        __syncthreads();   // drains vmcnt: staging complete

        float* __restrict__ outn =
            out + ((size_t)(n * N_ANG + k) * H_ + ty0) * W_ + tx0;
#pragma unroll
        for (int p = 0; p < 2; ++p) {
            float v[4];
#pragma unroll
            for (int j = 0; j < 4; ++j) {
                const float* __restrict__ b0 = &tile[ob[p][j]];
                // taps: (y0,x0)=b0[0], (y0,x1)=b0[1], (y1,x0)=b0[LP], (y1,x1)=b0[LP+1]
                v[j] = w00[p][j] * b0[0]
                     + w01[p][j] * b0[1]
                     + w10[p][j] * b0[LP]
                     + w11[p][j] * b0[LP + 1];
            }
            float4* dst = (float4*)(outn + (py0 + p * 16) * W_ + px);
            *dst = make_float4(v[0], v[1], v[2], v[3]);
        }
        __syncthreads();   // protect LDS before next image's staging
    }
}

extern "C" void kernel_launch(void* const* d_in, const int* in_sizes, int n_in,
                              void* d_out, int out_size, void* d_ws, size_t ws_size,
                              hipStream_t stream) {
    const float* img    = (const float*)d_in[0];
    const float* angles = (const float*)d_in[1];
    float* out          = (float*)d_out;

    dim3 block(256, 1, 1);
    dim3 grid(W_ / TX, H_ / TY, N_ANG * 2);  // 8 x 16 x 16 = 2048 blocks
    rotate_tile_kernel<<<grid, block, 0, stream>>>(img, angles, out);
}